// Round 6
// baseline (4153.025 us; speedup 1.0000x reference)
//
#include <hip/hip_runtime.h>
#include <hip/hip_bf16.h>
#include <stdint.h>

// Problem constants
constexpr int B_ = 32, N_ = 4096, D_ = 256, NH_ = 4, DH_ = 64, NS_ = 8;
constexpr float EPS_ = 1e-8f;

// Giles single-precision erfinv — same coefficients XLA uses for f32 erf_inv
__device__ inline float erfinv_f(float x) {
  float w = -logf((1.0f - x) * (1.0f + x));
  float p;
  if (w < 5.0f) {
    w = w - 2.5f;
    p = 2.81022636e-08f;
    p = 3.43273939e-07f + p * w;
    p = -3.5233877e-06f + p * w;
    p = -4.39150654e-06f + p * w;
    p = 0.00021858087f + p * w;
    p = -0.00125372503f + p * w;
    p = -0.00417768164f + p * w;
    p = 0.246640727f + p * w;
    p = 1.50140941f + p * w;
  } else {
    w = sqrtf(w) - 3.0f;
    p = -0.000200214257f;
    p = 0.000100950558f + p * w;
    p = 0.00134934322f + p * w;
    p = -0.00367342844f + p * w;
    p = 0.00573950773f + p * w;
    p = -0.0076224613f + p * w;
    p = 0.00943887047f + p * w;
    p = 1.00167406f + p * w;
    p = 2.83297682f + p * w;
  }
  return p * x;
}

// Threefry-2x32, 20 rounds (JAX PRNG), key (0, 42)
__device__ inline void threefry(unsigned k0, unsigned k1, unsigned& x0, unsigned& x1) {
  unsigned ks2 = k0 ^ k1 ^ 0x1BD11BDAu;
  x0 += k0; x1 += k1;
#define TF_R(r) { x0 += x1; x1 = (x1 << (r)) | (x1 >> (32 - (r))); x1 ^= x0; }
  TF_R(13) TF_R(15) TF_R(26) TF_R(6)
  x0 += k1; x1 += ks2 + 1u;
  TF_R(17) TF_R(29) TF_R(16) TF_R(24)
  x0 += ks2; x1 += k0 + 2u;
  TF_R(13) TF_R(15) TF_R(26) TF_R(6)
  x0 += k0; x1 += k1 + 3u;
  TF_R(17) TF_R(29) TF_R(16) TF_R(24)
  x0 += k1; x1 += ks2 + 4u;
  TF_R(13) TF_R(15) TF_R(26) TF_R(6)
  x0 += ks2; x1 += k0 + 5u;
#undef TF_R
}

__device__ inline float bits_to_normal(unsigned bits) {
  // fp32 path: uniform in [1,2) -> [0,1) -> [lo, 1) -> sqrt(2)*erfinv
  float f = __uint_as_float((bits >> 9) | 0x3F800000u) - 1.0f;
  const float lo = -0.99999994f;
  const float span = 2.0f;          // fp32(1.0 - nextafter(-1,0)) == 2.0
  float u = fmaxf(lo, f * span + lo);
  return 1.41421356f * erfinv_f(u); // fp32(sqrt(2))
}

// ---------- kernel 1: slot init — PARTITIONABLE threefry (jax >= 0.4.36 default) ----------
// Element e: counter = uint64(e) -> (hi=0, lo=e); key (0,42); bits = out_x0 ^ out_x1.
__global__ __launch_bounds__(256) void k_slots_init(const float* __restrict__ mu,
                                                    const float* __restrict__ logsigma,
                                                    float* __restrict__ slots) {
  unsigned e = blockIdx.x * 256u + threadIdx.x;   // [0, 65536)
  unsigned x0 = 0u, x1 = e;
  threefry(0u, 42u, x0, x1);
  unsigned bits = x0 ^ x1;
  float n = bits_to_normal(bits);
  int d = e & 255;
  slots[e] = mu[d] + expf(logsigma[d]) * n;
}

// ---------- kernel 2: q = LN(slots) @ Wq, pre-scaled by DH^-0.5 ----------
__global__ __launch_bounds__(256) void k_qproj(const float* __restrict__ slots,
                                               const float* __restrict__ ln_w,
                                               const float* __restrict__ ln_b,
                                               const float* __restrict__ Wq,
                                               float* __restrict__ qout) {
  __shared__ float sn[256];
  __shared__ float redA[4], redB[4];
  int row = blockIdx.x, t = threadIdx.x;
  float x = slots[row * 256 + t];
  float s = x, s2 = x * x;
#pragma unroll
  for (int off = 32; off; off >>= 1) { s += __shfl_xor(s, off); s2 += __shfl_xor(s2, off); }
  if ((t & 63) == 0) { redA[t >> 6] = s; redB[t >> 6] = s2; }
  __syncthreads();
  float ts = redA[0] + redA[1] + redA[2] + redA[3];
  float ts2 = redB[0] + redB[1] + redB[2] + redB[3];
  float m = ts * (1.0f / 256.0f);
  float var = ts2 * (1.0f / 256.0f) - m * m;
  float rstd = rsqrtf(var + 1e-5f);
  sn[t] = (x - m) * rstd * ln_w[t] + ln_b[t];
  __syncthreads();
  float a = 0.0f;
  for (int k = 0; k < 256; ++k) a += sn[k] * Wq[k * 256 + t];
  qout[row * 256 + t] = a * 0.125f;   // DH^-0.5 folded in
}

// ---------- kernel 3: FUSED LN(inputs) + K/V projection (fp32 LDS) + attention ----------
// Grid (128 token-chunks, 32 batch). Block = 256 threads, 32 tokens, 96 KB LDS.
__global__ __launch_bounds__(256) void k_fused_attn(
    const float* __restrict__ in,
    const float* __restrict__ ln_w, const float* __restrict__ ln_b,
    const float* __restrict__ Wk, const float* __restrict__ Wv,
    const float* __restrict__ qbuf,
    float* __restrict__ U, float* __restrict__ S) {
  __shared__ __align__(16) float ldsf[24576];   // 96 KB
  float* xs = ldsf;            // [32][256] LN'd inputs (phase 1-2)
  float* kf = ldsf + 8192;     // [32][256] fp32 K tile
  float* vf = ldsf + 16384;    // [32][256] fp32 V tile
  float* qs    = ldsf;         // [8][256]  (phase 3+, xs dead)
  float* redS  = ldsf + 2048;  // [2048]
  float* sredS = ldsf + 4096;  // [32]

  int b = blockIdx.y, chunk = blockIdx.x;
  int t = threadIdx.x;
  int wave = t >> 6, lane = t & 63;
  long row0 = (long)b * N_ + (long)chunk * 32;

  // ---- Phase 1: LN of 32 fp32 input rows -> xs ----
  for (int j = 0; j < 8; ++j) {
    int r = wave * 8 + j;
    const float4* rp = (const float4*)(in + (row0 + r) * D_);
    float4 v = rp[lane];
    float s = v.x + v.y + v.z + v.w;
    float s2 = v.x * v.x + v.y * v.y + v.z * v.z + v.w * v.w;
#pragma unroll
    for (int off = 32; off; off >>= 1) { s += __shfl_xor(s, off); s2 += __shfl_xor(s2, off); }
    float m = s * (1.0f / 256.0f);
    float var = s2 * (1.0f / 256.0f) - m * m;
    float rstd = rsqrtf(var + 1e-5f);
    int c = lane * 4;
    xs[r * 256 + c + 0] = (v.x - m) * rstd * ln_w[c + 0] + ln_b[c + 0];
    xs[r * 256 + c + 1] = (v.y - m) * rstd * ln_w[c + 1] + ln_b[c + 1];
    xs[r * 256 + c + 2] = (v.z - m) * rstd * ln_w[c + 2] + ln_b[c + 2];
    xs[r * 256 + c + 3] = (v.w - m) * rstd * ln_w[c + 3] + ln_b[c + 3];
  }
  __syncthreads();

  // ---- Phase 2: 32x512 projection, fp32 outputs to LDS ----
  {
    int tx = t & 31, ty = t >> 5;
    const float* W = (tx < 16) ? Wk : Wv;
    float* obf = (tx < 16) ? kf : vf;
    int col0 = (tx & 15) * 16;
    float acc2[4][16];
#pragma unroll
    for (int r = 0; r < 4; ++r)
#pragma unroll
      for (int c = 0; c < 16; ++c) acc2[r][c] = 0.0f;

    for (int k = 0; k < 256; ++k) {
      const float4* wp = (const float4*)(W + k * 256 + col0);
      float4 w0 = wp[0], w1 = wp[1], w2 = wp[2], w3 = wp[3];
#pragma unroll
      for (int r = 0; r < 4; ++r) {
        float x = xs[(ty * 4 + r) * 256 + k];
        acc2[r][0]  += x * w0.x; acc2[r][1]  += x * w0.y; acc2[r][2]  += x * w0.z; acc2[r][3]  += x * w0.w;
        acc2[r][4]  += x * w1.x; acc2[r][5]  += x * w1.y; acc2[r][6]  += x * w1.z; acc2[r][7]  += x * w1.w;
        acc2[r][8]  += x * w2.x; acc2[r][9]  += x * w2.y; acc2[r][10] += x * w2.z; acc2[r][11] += x * w2.w;
        acc2[r][12] += x * w3.x; acc2[r][13] += x * w3.y; acc2[r][14] += x * w3.z; acc2[r][15] += x * w3.w;
      }
    }
#pragma unroll
    for (int r = 0; r < 4; ++r) {
      float4* dst = (float4*)&obf[(ty * 4 + r) * 256 + col0];
      dst[0] = make_float4(acc2[r][0],  acc2[r][1],  acc2[r][2],  acc2[r][3]);
      dst[1] = make_float4(acc2[r][4],  acc2[r][5],  acc2[r][6],  acc2[r][7]);
      dst[2] = make_float4(acc2[r][8],  acc2[r][9],  acc2[r][10], acc2[r][11]);
      dst[3] = make_float4(acc2[r][12], acc2[r][13], acc2[r][14], acc2[r][15]);
    }
  }
  __syncthreads();

  // ---- Phase 3: q tile into (dead) xs region; zero reduction buffers ----
#pragma unroll
  for (int i = 0; i < 8; ++i) qs[i * 256 + t] = qbuf[((long)b * 8 + i) * 256 + t];
  for (int e = t; e < 2048; e += 256) redS[e] = 0.0f;
  if (t < 32) sredS[t] = 0.0f;
  __syncthreads();

  // ---- Phase 4: attention over the 32 local tokens (all fp32) ----
  // lane -> head h = lane/16, dims dh = (lane%16)*4 .. +3
  float qv[8][4];
#pragma unroll
  for (int i = 0; i < 8; ++i) {
    float4 qq = *(const float4*)&qs[i * 256 + lane * 4];
    qv[i][0] = qq.x; qv[i][1] = qq.y; qv[i][2] = qq.z; qv[i][3] = qq.w;
  }
  float acc[8][4];
  float sacc[8];
#pragma unroll
  for (int i = 0; i < 8; ++i) {
    sacc[i] = 0.0f;
    acc[i][0] = acc[i][1] = acc[i][2] = acc[i][3] = 0.0f;
  }

  for (int jj = wave; jj < 32; jj += 4) {
    float4 k4 = *(const float4*)&kf[jj * 256 + lane * 4];
    float d[8];
#pragma unroll
    for (int i = 0; i < 8; ++i)
      d[i] = qv[i][0] * k4.x + qv[i][1] * k4.y + qv[i][2] * k4.z + qv[i][3] * k4.w;
#pragma unroll
    for (int off2 = 1; off2 < 16; off2 <<= 1) {
#pragma unroll
      for (int i = 0; i < 8; ++i) d[i] += __shfl_xor(d[i], off2);
    }
    // softmax over 8 slots (per token, per head) — precise expf
    float mx = d[0];
#pragma unroll
    for (int i = 1; i < 8; ++i) mx = fmaxf(mx, d[i]);
    float e[8], sum = 0.0f;
#pragma unroll
    for (int i = 0; i < 8; ++i) { e[i] = expf(d[i] - mx); sum += e[i]; }
    float inv = 1.0f / sum;

    float4 v4 = *(const float4*)&vf[jj * 256 + lane * 4];
#pragma unroll
    for (int i = 0; i < 8; ++i) {
      float a = e[i] * inv + EPS_;   // attn = softmax + eps (L1 denom includes eps)
      sacc[i] += a;
      acc[i][0] += a * v4.x; acc[i][1] += a * v4.y; acc[i][2] += a * v4.z; acc[i][3] += a * v4.w;
    }
  }

  // ---- Phase 5: LDS reduction across 4 waves ----
#pragma unroll
  for (int i = 0; i < 8; ++i) {
    atomicAdd(&redS[i * 256 + lane * 4 + 0], acc[i][0]);
    atomicAdd(&redS[i * 256 + lane * 4 + 1], acc[i][1]);
    atomicAdd(&redS[i * 256 + lane * 4 + 2], acc[i][2]);
    atomicAdd(&redS[i * 256 + lane * 4 + 3], acc[i][3]);
  }
  if ((lane & 15) == 0) {
    int h = lane >> 4;
#pragma unroll
    for (int i = 0; i < 8; ++i) atomicAdd(&sredS[i * 4 + h], sacc[i]);
  }
  __syncthreads();

  // ---- Phase 6: one global atomic per element ----
  for (int e = t; e < 2048; e += 256)
    atomicAdd(&U[((long)b * 8 + (e >> 8)) * 256 + (e & 255)], redS[e]);
  if (t < 32) atomicAdd(&S[b * 32 + t], sredS[t]);
}

// ---------- kernel 4: normalize + Wc + GRU + LN + MLP (fp32 everything) ----------
__global__ __launch_bounds__(256) void k_slot_update(
    const float* __restrict__ U, const float* __restrict__ S,
    float* __restrict__ slots,
    const float* __restrict__ Wc,
    const float* __restrict__ w_ih, const float* __restrict__ w_hh,
    const float* __restrict__ b_ih, const float* __restrict__ b_hh,
    const float* __restrict__ ln_m_w, const float* __restrict__ ln_m_b,
    const float* __restrict__ w1, const float* __restrict__ b1,
    const float* __restrict__ w2, const float* __restrict__ b2,
    float* __restrict__ out_final, int write_out) {
  __shared__ float un[256], upd[256], hprev[256], mbuf[256], hid[128];
  __shared__ float redA[4], redB[4];
  int row = blockIdx.x, t = threadIdx.x;

  float denom = S[row * 4 + (t >> 6)];   // S[b][slot][h], h = t/64
  un[t] = U[(long)row * 256 + t] / denom;
  float hp = slots[(long)row * 256 + t];
  hprev[t] = hp;
  __syncthreads();

  // updates @ Wc
  float a = 0.0f;
  for (int k = 0; k < 256; ++k) a += un[k] * Wc[k * 256 + t];
  upd[t] = a;
  __syncthreads();

  // GRU gates (PyTorch order r,z,n)
  float gxr = b_ih[t], gxz = b_ih[256 + t], gxn = b_ih[512 + t];
  float ghr = b_hh[t], ghz = b_hh[256 + t], ghn = b_hh[512 + t];
  const float4* u4 = (const float4*)upd;
  const float4* h4 = (const float4*)hprev;
  const float4* wr = (const float4*)(w_ih + (long)t * 256);
  const float4* wz = (const float4*)(w_ih + (long)(256 + t) * 256);
  const float4* wn = (const float4*)(w_ih + (long)(512 + t) * 256);
  const float4* vr = (const float4*)(w_hh + (long)t * 256);
  const float4* vz = (const float4*)(w_hh + (long)(256 + t) * 256);
  const float4* vn = (const float4*)(w_hh + (long)(512 + t) * 256);
  for (int k = 0; k < 64; ++k) {
    float4 uu = u4[k], hh = h4[k], w;
    w = wr[k]; gxr += uu.x * w.x + uu.y * w.y + uu.z * w.z + uu.w * w.w;
    w = wz[k]; gxz += uu.x * w.x + uu.y * w.y + uu.z * w.z + uu.w * w.w;
    w = wn[k]; gxn += uu.x * w.x + uu.y * w.y + uu.z * w.z + uu.w * w.w;
    w = vr[k]; ghr += hh.x * w.x + hh.y * w.y + hh.z * w.z + hh.w * w.w;
    w = vz[k]; ghz += hh.x * w.x + hh.y * w.y + hh.z * w.z + hh.w * w.w;
    w = vn[k]; ghn += hh.x * w.x + hh.y * w.y + hh.z * w.z + hh.w * w.w;
  }
  float r = 1.0f / (1.0f + expf(-(gxr + ghr)));
  float z = 1.0f / (1.0f + expf(-(gxz + ghz)));
  float ng = tanhf(gxn + r * ghn);
  float sv = (1.0f - z) * ng + z * hp;

  // LayerNorm(sv)
  float s1 = sv, s2v = sv * sv;
#pragma unroll
  for (int off = 32; off; off >>= 1) { s1 += __shfl_xor(s1, off); s2v += __shfl_xor(s2v, off); }
  if ((t & 63) == 0) { redA[t >> 6] = s1; redB[t >> 6] = s2v; }
  __syncthreads();
  float ts = redA[0] + redA[1] + redA[2] + redA[3];
  float ts2 = redB[0] + redB[1] + redB[2] + redB[3];
  float mean = ts * (1.0f / 256.0f);
  float var = ts2 * (1.0f / 256.0f) - mean * mean;
  float rstd = rsqrtf(var + 1e-5f);
  mbuf[t] = (sv - mean) * rstd * ln_m_w[t] + ln_m_b[t];
  __syncthreads();

  // MLP: 256 -> 128 (relu) -> 256, residual
  if (t < 128) {
    float hv = b1[t];
    for (int d = 0; d < 256; ++d) hv += mbuf[d] * w1[d * 128 + t];
    hid[t] = fmaxf(hv, 0.0f);
  }
  __syncthreads();
  float o = b2[t];
  for (int j = 0; j < 128; ++j) o += hid[j] * w2[j * 256 + t];
  float res = sv + o;
  slots[(long)row * 256 + t] = res;
  if (write_out) out_final[(long)row * 256 + t] = res;   // fp32 output
}

// ---------- launch ----------
extern "C" void kernel_launch(void* const* d_in, const int* in_sizes, int n_in,
                              void* d_out, int out_size, void* d_ws, size_t ws_size,
                              hipStream_t stream) {
  (void)in_sizes; (void)n_in; (void)out_size; (void)ws_size;
  const float* inputs        = (const float*)d_in[0];
  const float* slots_mu      = (const float*)d_in[1];
  const float* slots_logsig  = (const float*)d_in[2];
  const float* ln_in_w       = (const float*)d_in[3];
  const float* ln_in_b       = (const float*)d_in[4];
  const float* ln_s_w        = (const float*)d_in[5];
  const float* ln_s_b        = (const float*)d_in[6];
  const float* Wq            = (const float*)d_in[7];
  const float* Wk            = (const float*)d_in[8];
  const float* Wv            = (const float*)d_in[9];
  const float* Wc            = (const float*)d_in[10];
  const float* w_ih          = (const float*)d_in[11];
  const float* w_hh          = (const float*)d_in[12];
  const float* b_ih          = (const float*)d_in[13];
  const float* b_hh          = (const float*)d_in[14];
  const float* ln_m_w        = (const float*)d_in[15];
  const float* ln_m_b        = (const float*)d_in[16];
  const float* w1            = (const float*)d_in[17];
  const float* b1            = (const float*)d_in[18];
  const float* w2            = (const float*)d_in[19];
  const float* b2            = (const float*)d_in[20];

  // Workspace (fp32 internal state): 772 KB total.
  char* ws = (char*)d_ws;
  float* slots = (float*)ws;                 // 256 KB
  float* qbuf  = (float*)(ws + 262144);      // 256 KB
  float* U     = (float*)(ws + 524288);      // 256 KB
  float* S     = (float*)(ws + 786432);      // 4 KB

  k_slots_init<<<256, 256, 0, stream>>>(slots_mu, slots_logsig, slots);

  for (int it = 0; it < 3; ++it) {
    hipMemsetAsync(U, 0, (65536 + 1024) * sizeof(float), stream);
    k_qproj<<<256, 256, 0, stream>>>(slots, ln_s_w, ln_s_b, Wq, qbuf);
    k_fused_attn<<<dim3(128, 32), 256, 0, stream>>>(inputs, ln_in_w, ln_in_b,
                                                    Wk, Wv, qbuf, U, S);
    k_slot_update<<<256, 256, 0, stream>>>(U, S, slots, Wc, w_ih, w_hh, b_ih, b_hh,
                                           ln_m_w, ln_m_b, w1, b1, w2, b2,
                                           (float*)d_out, it == 2 ? 1 : 0);
  }
}

// Round 7
// 1665.663 us; speedup vs baseline: 2.4933x; 2.4933x over previous
//
#include <hip/hip_runtime.h>
#include <hip/hip_bf16.h>
#include <stdint.h>

// Problem constants
constexpr int B_ = 32, N_ = 4096, D_ = 256, NH_ = 4, DH_ = 64, NS_ = 8;
constexpr float EPS_ = 1e-8f;

typedef unsigned short u16;

__device__ inline u16 f2bf(float f) {
  unsigned u = __float_as_uint(f);
  unsigned r = u + 0x7FFFu + ((u >> 16) & 1u);   // RNE
  return (u16)(r >> 16);
}
__device__ inline float bf2f(u16 u) {
  return __uint_as_float(((unsigned)u) << 16);
}

// Giles single-precision erfinv — same coefficients XLA uses for f32 erf_inv
__device__ inline float erfinv_f(float x) {
  float w = -logf((1.0f - x) * (1.0f + x));
  float p;
  if (w < 5.0f) {
    w = w - 2.5f;
    p = 2.81022636e-08f;
    p = 3.43273939e-07f + p * w;
    p = -3.5233877e-06f + p * w;
    p = -4.39150654e-06f + p * w;
    p = 0.00021858087f + p * w;
    p = -0.00125372503f + p * w;
    p = -0.00417768164f + p * w;
    p = 0.246640727f + p * w;
    p = 1.50140941f + p * w;
  } else {
    w = sqrtf(w) - 3.0f;
    p = -0.000200214257f;
    p = 0.000100950558f + p * w;
    p = 0.00134934322f + p * w;
    p = -0.00367342844f + p * w;
    p = 0.00573950773f + p * w;
    p = -0.0076224613f + p * w;
    p = 0.00943887047f + p * w;
    p = 1.00167406f + p * w;
    p = 2.83297682f + p * w;
  }
  return p * x;
}

// Threefry-2x32, 20 rounds (JAX PRNG), key (0, 42)
__device__ inline void threefry(unsigned k0, unsigned k1, unsigned& x0, unsigned& x1) {
  unsigned ks2 = k0 ^ k1 ^ 0x1BD11BDAu;
  x0 += k0; x1 += k1;
#define TF_R(r) { x0 += x1; x1 = (x1 << (r)) | (x1 >> (32 - (r))); x1 ^= x0; }
  TF_R(13) TF_R(15) TF_R(26) TF_R(6)
  x0 += k1; x1 += ks2 + 1u;
  TF_R(17) TF_R(29) TF_R(16) TF_R(24)
  x0 += ks2; x1 += k0 + 2u;
  TF_R(13) TF_R(15) TF_R(26) TF_R(6)
  x0 += k0; x1 += k1 + 3u;
  TF_R(17) TF_R(29) TF_R(16) TF_R(24)
  x0 += k1; x1 += ks2 + 4u;
  TF_R(13) TF_R(15) TF_R(26) TF_R(6)
  x0 += ks2; x1 += k0 + 5u;
#undef TF_R
}

__device__ inline float bits_to_normal(unsigned bits) {
  float f = __uint_as_float((bits >> 9) | 0x3F800000u) - 1.0f;
  const float lo = -0.99999994f;
  const float span = 2.0f;
  float u = fmaxf(lo, f * span + lo);
  return 1.41421356f * erfinv_f(u);
}

// ---------- kernel 1: slot init — partitionable threefry (jax >= 0.4.36 default) ----------
__global__ __launch_bounds__(256) void k_slots_init(const float* __restrict__ mu,
                                                    const float* __restrict__ logsigma,
                                                    float* __restrict__ slots) {
  unsigned e = blockIdx.x * 256u + threadIdx.x;   // [0, 65536)
  unsigned x0 = 0u, x1 = e;
  threefry(0u, 42u, x0, x1);
  unsigned bits = x0 ^ x1;
  float n = bits_to_normal(bits);
  int d = e & 255;
  slots[e] = mu[d] + expf(logsigma[d]) * n;
}

// ---------- kernel 2: q = LN(slots) @ Wq, pre-scaled by DH^-0.5 ----------
__global__ __launch_bounds__(256) void k_qproj(const float* __restrict__ slots,
                                               const float* __restrict__ ln_w,
                                               const float* __restrict__ ln_b,
                                               const float* __restrict__ Wq,
                                               float* __restrict__ qout) {
  __shared__ float sn[256];
  __shared__ float redA[4], redB[4];
  int row = blockIdx.x, t = threadIdx.x;
  float x = slots[row * 256 + t];
  float s = x, s2 = x * x;
#pragma unroll
  for (int off = 32; off; off >>= 1) { s += __shfl_xor(s, off); s2 += __shfl_xor(s2, off); }
  if ((t & 63) == 0) { redA[t >> 6] = s; redB[t >> 6] = s2; }
  __syncthreads();
  float ts = redA[0] + redA[1] + redA[2] + redA[3];
  float ts2 = redB[0] + redB[1] + redB[2] + redB[3];
  float m = ts * (1.0f / 256.0f);
  float var = ts2 * (1.0f / 256.0f) - m * m;
  float rstd = rsqrtf(var + 1e-5f);
  sn[t] = (x - m) * rstd * ln_w[t] + ln_b[t];
  __syncthreads();
  float a = 0.0f;
  for (int k = 0; k < 256; ++k) a += sn[k] * Wq[k * 256 + t];
  qout[row * 256 + t] = a * 0.125f;
}

// ---------- kernel 3a (fast path): LN(inputs) + K/V projection -> bf16 global cache ----------
// Block = 256 threads, 32 rows, 32 KB LDS (3 blocks/CU at VGPR~132).
__global__ __launch_bounds__(256) void k_proj(
    const float* __restrict__ in,
    const float* __restrict__ ln_w, const float* __restrict__ ln_b,
    const float* __restrict__ Wk, const float* __restrict__ Wv,
    u16* __restrict__ kbuf, u16* __restrict__ vbuf) {
  __shared__ __align__(16) float xs[32 * 256];   // 32 KB
  int t = threadIdx.x;
  int wave = t >> 6, lane = t & 63;
  long row0 = (long)blockIdx.x * 32;

  // Phase 1: LN of 32 rows
  for (int j = 0; j < 8; ++j) {
    int r = wave * 8 + j;
    const float4* rp = (const float4*)(in + (row0 + r) * D_);
    float4 v = rp[lane];
    float s = v.x + v.y + v.z + v.w;
    float s2 = v.x * v.x + v.y * v.y + v.z * v.z + v.w * v.w;
#pragma unroll
    for (int off = 32; off; off >>= 1) { s += __shfl_xor(s, off); s2 += __shfl_xor(s2, off); }
    float m = s * (1.0f / 256.0f);
    float var = s2 * (1.0f / 256.0f) - m * m;
    float rstd = rsqrtf(var + 1e-5f);
    int c = lane * 4;
    xs[r * 256 + c + 0] = (v.x - m) * rstd * ln_w[c + 0] + ln_b[c + 0];
    xs[r * 256 + c + 1] = (v.y - m) * rstd * ln_w[c + 1] + ln_b[c + 1];
    xs[r * 256 + c + 2] = (v.z - m) * rstd * ln_w[c + 2] + ln_b[c + 2];
    xs[r * 256 + c + 3] = (v.w - m) * rstd * ln_w[c + 3] + ln_b[c + 3];
  }
  __syncthreads();

  // Phase 2: 32x512 GEMM tile; tx<16 -> Wk cols, else Wv cols
  int tx = t & 31, ty = t >> 5;
  const float* W = (tx < 16) ? Wk : Wv;
  u16* outp = (tx < 16) ? kbuf : vbuf;
  int col0 = (tx & 15) * 16;
  float acc[4][16];
#pragma unroll
  for (int r = 0; r < 4; ++r)
#pragma unroll
    for (int c = 0; c < 16; ++c) acc[r][c] = 0.0f;

  for (int k = 0; k < 256; ++k) {
    const float4* wp = (const float4*)(W + k * 256 + col0);
    float4 w0 = wp[0], w1 = wp[1], w2 = wp[2], w3 = wp[3];
#pragma unroll
    for (int r = 0; r < 4; ++r) {
      float x = xs[(ty * 4 + r) * 256 + k];
      acc[r][0]  += x * w0.x; acc[r][1]  += x * w0.y; acc[r][2]  += x * w0.z; acc[r][3]  += x * w0.w;
      acc[r][4]  += x * w1.x; acc[r][5]  += x * w1.y; acc[r][6]  += x * w1.z; acc[r][7]  += x * w1.w;
      acc[r][8]  += x * w2.x; acc[r][9]  += x * w2.y; acc[r][10] += x * w2.z; acc[r][11] += x * w2.w;
      acc[r][12] += x * w3.x; acc[r][13] += x * w3.y; acc[r][14] += x * w3.z; acc[r][15] += x * w3.w;
    }
  }

#pragma unroll
  for (int r = 0; r < 4; ++r) {
    long row = row0 + ty * 4 + r;
    unsigned pk[8];
#pragma unroll
    for (int c = 0; c < 8; ++c)
      pk[c] = (unsigned)f2bf(acc[r][2 * c]) | ((unsigned)f2bf(acc[r][2 * c + 1]) << 16);
    uint4* dst = (uint4*)(outp + row * 256 + col0);
    dst[0] = make_uint4(pk[0], pk[1], pk[2], pk[3]);
    dst[1] = make_uint4(pk[4], pk[5], pk[6], pk[7]);
  }
}

// ---------- kernel 3b (fast path): streaming attention over cached bf16 K/V ----------
// Grid (32 chunks, 32 b); block = 256 threads; each block does 128 tokens.
__global__ __launch_bounds__(256) void k_attn(
    const float* __restrict__ qbuf,
    const u16* __restrict__ kbuf, const u16* __restrict__ vbuf,
    float* __restrict__ U, float* __restrict__ S) {
  __shared__ float redS[2048];
  __shared__ float sredS[32];
  int b = blockIdx.y, chunk = blockIdx.x;
  int t = threadIdx.x;
  int wave = t >> 6, lane = t & 63;

  // zero reduction buffers
  for (int e = t; e < 2048; e += 256) redS[e] = 0.0f;
  if (t < 32) sredS[t] = 0.0f;

  // q for this lane's (head, 4 dims), all 8 slots
  float qv[8][4];
#pragma unroll
  for (int i = 0; i < 8; ++i) {
    float4 qq = *(const float4*)(qbuf + ((long)(b * 8 + i)) * 256 + lane * 4);
    qv[i][0] = qq.x; qv[i][1] = qq.y; qv[i][2] = qq.z; qv[i][3] = qq.w;
  }
  float acc[8][4];
  float sacc[8];
#pragma unroll
  for (int i = 0; i < 8; ++i) {
    sacc[i] = 0.0f;
    acc[i][0] = acc[i][1] = acc[i][2] = acc[i][3] = 0.0f;
  }
  __syncthreads();

  long jbase = (long)b * N_ + chunk * 128;
  for (int jj = wave; jj < 128; jj += 4) {
    long off = (jbase + jj) * 256 + lane * 4;
    ushort4 k4 = *(const ushort4*)(kbuf + off);
    ushort4 v4 = *(const ushort4*)(vbuf + off);
    float k0 = bf2f(k4.x), k1 = bf2f(k4.y), k2 = bf2f(k4.z), k3 = bf2f(k4.w);

    float d[8];
#pragma unroll
    for (int i = 0; i < 8; ++i)
      d[i] = qv[i][0] * k0 + qv[i][1] * k1 + qv[i][2] * k2 + qv[i][3] * k3;
#pragma unroll
    for (int off2 = 1; off2 < 16; off2 <<= 1) {
#pragma unroll
      for (int i = 0; i < 8; ++i) d[i] += __shfl_xor(d[i], off2);
    }
    float mx = d[0];
#pragma unroll
    for (int i = 1; i < 8; ++i) mx = fmaxf(mx, d[i]);
    float e[8], sum = 0.0f;
#pragma unroll
    for (int i = 0; i < 8; ++i) { e[i] = expf(d[i] - mx); sum += e[i]; }
    float inv = 1.0f / sum;

    float v0 = bf2f(v4.x), v1 = bf2f(v4.y), v2 = bf2f(v4.z), v3 = bf2f(v4.w);
#pragma unroll
    for (int i = 0; i < 8; ++i) {
      float a = e[i] * inv + EPS_;
      sacc[i] += a;
      acc[i][0] += a * v0; acc[i][1] += a * v1; acc[i][2] += a * v2; acc[i][3] += a * v3;
    }
  }

  // LDS reduce across waves
#pragma unroll
  for (int i = 0; i < 8; ++i) {
    atomicAdd(&redS[i * 256 + lane * 4 + 0], acc[i][0]);
    atomicAdd(&redS[i * 256 + lane * 4 + 1], acc[i][1]);
    atomicAdd(&redS[i * 256 + lane * 4 + 2], acc[i][2]);
    atomicAdd(&redS[i * 256 + lane * 4 + 3], acc[i][3]);
  }
  if ((lane & 15) == 0) {
    int h = lane >> 4;
#pragma unroll
    for (int i = 0; i < 8; ++i) atomicAdd(&sredS[i * 4 + h], sacc[i]);
  }
  __syncthreads();

  for (int e = t; e < 2048; e += 256)
    atomicAdd(&U[((long)b * 8 + (e >> 8)) * 256 + (e & 255)], redS[e]);
  if (t < 32) atomicAdd(&S[b * 32 + t], sredS[t]);
}

// ---------- kernel 3-fallback: R6's fused LN+proj+attention (96 KB LDS) ----------
__global__ __launch_bounds__(256) void k_fused_attn(
    const float* __restrict__ in,
    const float* __restrict__ ln_w, const float* __restrict__ ln_b,
    const float* __restrict__ Wk, const float* __restrict__ Wv,
    const float* __restrict__ qbuf,
    float* __restrict__ U, float* __restrict__ S) {
  __shared__ __align__(16) float ldsf[24576];
  float* xs = ldsf;
  float* kf = ldsf + 8192;
  float* vf = ldsf + 16384;
  float* qs    = ldsf;
  float* redS  = ldsf + 2048;
  float* sredS = ldsf + 4096;

  int b = blockIdx.y, chunk = blockIdx.x;
  int t = threadIdx.x;
  int wave = t >> 6, lane = t & 63;
  long row0 = (long)b * N_ + (long)chunk * 32;

  for (int j = 0; j < 8; ++j) {
    int r = wave * 8 + j;
    const float4* rp = (const float4*)(in + (row0 + r) * D_);
    float4 v = rp[lane];
    float s = v.x + v.y + v.z + v.w;
    float s2 = v.x * v.x + v.y * v.y + v.z * v.z + v.w * v.w;
#pragma unroll
    for (int off = 32; off; off >>= 1) { s += __shfl_xor(s, off); s2 += __shfl_xor(s2, off); }
    float m = s * (1.0f / 256.0f);
    float var = s2 * (1.0f / 256.0f) - m * m;
    float rstd = rsqrtf(var + 1e-5f);
    int c = lane * 4;
    xs[r * 256 + c + 0] = (v.x - m) * rstd * ln_w[c + 0] + ln_b[c + 0];
    xs[r * 256 + c + 1] = (v.y - m) * rstd * ln_w[c + 1] + ln_b[c + 1];
    xs[r * 256 + c + 2] = (v.z - m) * rstd * ln_w[c + 2] + ln_b[c + 2];
    xs[r * 256 + c + 3] = (v.w - m) * rstd * ln_w[c + 3] + ln_b[c + 3];
  }
  __syncthreads();

  {
    int tx = t & 31, ty = t >> 5;
    const float* W = (tx < 16) ? Wk : Wv;
    float* obf = (tx < 16) ? kf : vf;
    int col0 = (tx & 15) * 16;
    float acc2[4][16];
#pragma unroll
    for (int r = 0; r < 4; ++r)
#pragma unroll
      for (int c = 0; c < 16; ++c) acc2[r][c] = 0.0f;

    for (int k = 0; k < 256; ++k) {
      const float4* wp = (const float4*)(W + k * 256 + col0);
      float4 w0 = wp[0], w1 = wp[1], w2 = wp[2], w3 = wp[3];
#pragma unroll
      for (int r = 0; r < 4; ++r) {
        float x = xs[(ty * 4 + r) * 256 + k];
        acc2[r][0]  += x * w0.x; acc2[r][1]  += x * w0.y; acc2[r][2]  += x * w0.z; acc2[r][3]  += x * w0.w;
        acc2[r][4]  += x * w1.x; acc2[r][5]  += x * w1.y; acc2[r][6]  += x * w1.z; acc2[r][7]  += x * w1.w;
        acc2[r][8]  += x * w2.x; acc2[r][9]  += x * w2.y; acc2[r][10] += x * w2.z; acc2[r][11] += x * w2.w;
        acc2[r][12] += x * w3.x; acc2[r][13] += x * w3.y; acc2[r][14] += x * w3.z; acc2[r][15] += x * w3.w;
      }
    }
#pragma unroll
    for (int r = 0; r < 4; ++r) {
      float4* dst = (float4*)&obf[(ty * 4 + r) * 256 + col0];
      dst[0] = make_float4(acc2[r][0],  acc2[r][1],  acc2[r][2],  acc2[r][3]);
      dst[1] = make_float4(acc2[r][4],  acc2[r][5],  acc2[r][6],  acc2[r][7]);
      dst[2] = make_float4(acc2[r][8],  acc2[r][9],  acc2[r][10], acc2[r][11]);
      dst[3] = make_float4(acc2[r][12], acc2[r][13], acc2[r][14], acc2[r][15]);
    }
  }
  __syncthreads();

#pragma unroll
  for (int i = 0; i < 8; ++i) qs[i * 256 + t] = qbuf[((long)b * 8 + i) * 256 + t];
  for (int e = t; e < 2048; e += 256) redS[e] = 0.0f;
  if (t < 32) sredS[t] = 0.0f;
  __syncthreads();

  float qv[8][4];
#pragma unroll
  for (int i = 0; i < 8; ++i) {
    float4 qq = *(const float4*)&qs[i * 256 + lane * 4];
    qv[i][0] = qq.x; qv[i][1] = qq.y; qv[i][2] = qq.z; qv[i][3] = qq.w;
  }
  float acc[8][4];
  float sacc[8];
#pragma unroll
  for (int i = 0; i < 8; ++i) {
    sacc[i] = 0.0f;
    acc[i][0] = acc[i][1] = acc[i][2] = acc[i][3] = 0.0f;
  }

  for (int jj = wave; jj < 32; jj += 4) {
    float4 k4 = *(const float4*)&kf[jj * 256 + lane * 4];
    float d[8];
#pragma unroll
    for (int i = 0; i < 8; ++i)
      d[i] = qv[i][0] * k4.x + qv[i][1] * k4.y + qv[i][2] * k4.z + qv[i][3] * k4.w;
#pragma unroll
    for (int off2 = 1; off2 < 16; off2 <<= 1) {
#pragma unroll
      for (int i = 0; i < 8; ++i) d[i] += __shfl_xor(d[i], off2);
    }
    float mx = d[0];
#pragma unroll
    for (int i = 1; i < 8; ++i) mx = fmaxf(mx, d[i]);
    float e[8], sum = 0.0f;
#pragma unroll
    for (int i = 0; i < 8; ++i) { e[i] = expf(d[i] - mx); sum += e[i]; }
    float inv = 1.0f / sum;

    float4 v4 = *(const float4*)&vf[jj * 256 + lane * 4];
#pragma unroll
    for (int i = 0; i < 8; ++i) {
      float a = e[i] * inv + EPS_;
      sacc[i] += a;
      acc[i][0] += a * v4.x; acc[i][1] += a * v4.y; acc[i][2] += a * v4.z; acc[i][3] += a * v4.w;
    }
  }

#pragma unroll
  for (int i = 0; i < 8; ++i) {
    atomicAdd(&redS[i * 256 + lane * 4 + 0], acc[i][0]);
    atomicAdd(&redS[i * 256 + lane * 4 + 1], acc[i][1]);
    atomicAdd(&redS[i * 256 + lane * 4 + 2], acc[i][2]);
    atomicAdd(&redS[i * 256 + lane * 4 + 3], acc[i][3]);
  }
  if ((lane & 15) == 0) {
    int h = lane >> 4;
#pragma unroll
    for (int i = 0; i < 8; ++i) atomicAdd(&sredS[i * 4 + h], sacc[i]);
  }
  __syncthreads();

  for (int e = t; e < 2048; e += 256)
    atomicAdd(&U[((long)b * 8 + (e >> 8)) * 256 + (e & 255)], redS[e]);
  if (t < 32) atomicAdd(&S[b * 32 + t], sredS[t]);
}

// ---------- kernel 4: normalize + Wc + GRU + LN + MLP ----------
__global__ __launch_bounds__(256) void k_slot_update(
    const float* __restrict__ U, const float* __restrict__ S,
    float* __restrict__ slots,
    const float* __restrict__ Wc,
    const float* __restrict__ w_ih, const float* __restrict__ w_hh,
    const float* __restrict__ b_ih, const float* __restrict__ b_hh,
    const float* __restrict__ ln_m_w, const float* __restrict__ ln_m_b,
    const float* __restrict__ w1, const float* __restrict__ b1,
    const float* __restrict__ w2, const float* __restrict__ b2,
    float* __restrict__ out_final, int write_out) {
  __shared__ float un[256], upd[256], hprev[256], mbuf[256], hid[128];
  __shared__ float redA[4], redB[4];
  int row = blockIdx.x, t = threadIdx.x;

  float denom = S[row * 4 + (t >> 6)];
  un[t] = U[(long)row * 256 + t] / denom;
  float hp = slots[(long)row * 256 + t];
  hprev[t] = hp;
  __syncthreads();

  float a = 0.0f;
  for (int k = 0; k < 256; ++k) a += un[k] * Wc[k * 256 + t];
  upd[t] = a;
  __syncthreads();

  float gxr = b_ih[t], gxz = b_ih[256 + t], gxn = b_ih[512 + t];
  float ghr = b_hh[t], ghz = b_hh[256 + t], ghn = b_hh[512 + t];
  const float4* u4 = (const float4*)upd;
  const float4* h4 = (const float4*)hprev;
  const float4* wr = (const float4*)(w_ih + (long)t * 256);
  const float4* wz = (const float4*)(w_ih + (long)(256 + t) * 256);
  const float4* wn = (const float4*)(w_ih + (long)(512 + t) * 256);
  const float4* vr = (const float4*)(w_hh + (long)t * 256);
  const float4* vz = (const float4*)(w_hh + (long)(256 + t) * 256);
  const float4* vn = (const float4*)(w_hh + (long)(512 + t) * 256);
  for (int k = 0; k < 64; ++k) {
    float4 uu = u4[k], hh = h4[k], w;
    w = wr[k]; gxr += uu.x * w.x + uu.y * w.y + uu.z * w.z + uu.w * w.w;
    w = wz[k]; gxz += uu.x * w.x + uu.y * w.y + uu.z * w.z + uu.w * w.w;
    w = wn[k]; gxn += uu.x * w.x + uu.y * w.y + uu.z * w.z + uu.w * w.w;
    w = vr[k]; ghr += hh.x * w.x + hh.y * w.y + hh.z * w.z + hh.w * w.w;
    w = vz[k]; ghz += hh.x * w.x + hh.y * w.y + hh.z * w.z + hh.w * w.w;
    w = vn[k]; ghn += hh.x * w.x + hh.y * w.y + hh.z * w.z + hh.w * w.w;
  }
  float r = 1.0f / (1.0f + expf(-(gxr + ghr)));
  float z = 1.0f / (1.0f + expf(-(gxz + ghz)));
  float ng = tanhf(gxn + r * ghn);
  float sv = (1.0f - z) * ng + z * hp;

  float s1 = sv, s2v = sv * sv;
#pragma unroll
  for (int off = 32; off; off >>= 1) { s1 += __shfl_xor(s1, off); s2v += __shfl_xor(s2v, off); }
  if ((t & 63) == 0) { redA[t >> 6] = s1; redB[t >> 6] = s2v; }
  __syncthreads();
  float ts = redA[0] + redA[1] + redA[2] + redA[3];
  float ts2 = redB[0] + redB[1] + redB[2] + redB[3];
  float mean = ts * (1.0f / 256.0f);
  float var = ts2 * (1.0f / 256.0f) - mean * mean;
  float rstd = rsqrtf(var + 1e-5f);
  mbuf[t] = (sv - mean) * rstd * ln_m_w[t] + ln_m_b[t];
  __syncthreads();

  if (t < 128) {
    float hv = b1[t];
    for (int d = 0; d < 256; ++d) hv += mbuf[d] * w1[d * 128 + t];
    hid[t] = fmaxf(hv, 0.0f);
  }
  __syncthreads();
  float o = b2[t];
  for (int j = 0; j < 128; ++j) o += hid[j] * w2[j * 256 + t];
  float res = sv + o;
  slots[(long)row * 256 + t] = res;
  if (write_out) out_final[(long)row * 256 + t] = res;
}

// ---------- launch ----------
extern "C" void kernel_launch(void* const* d_in, const int* in_sizes, int n_in,
                              void* d_out, int out_size, void* d_ws, size_t ws_size,
                              hipStream_t stream) {
  (void)in_sizes; (void)n_in; (void)out_size;
  const float* inputs        = (const float*)d_in[0];
  const float* slots_mu      = (const float*)d_in[1];
  const float* slots_logsig  = (const float*)d_in[2];
  const float* ln_in_w       = (const float*)d_in[3];
  const float* ln_in_b       = (const float*)d_in[4];
  const float* ln_s_w        = (const float*)d_in[5];
  const float* ln_s_b        = (const float*)d_in[6];
  const float* Wq            = (const float*)d_in[7];
  const float* Wk            = (const float*)d_in[8];
  const float* Wv            = (const float*)d_in[9];
  const float* Wc            = (const float*)d_in[10];
  const float* w_ih          = (const float*)d_in[11];
  const float* w_hh          = (const float*)d_in[12];
  const float* b_ih          = (const float*)d_in[13];
  const float* b_hh          = (const float*)d_in[14];
  const float* ln_m_w        = (const float*)d_in[15];
  const float* ln_m_b        = (const float*)d_in[16];
  const float* w1            = (const float*)d_in[17];
  const float* b1            = (const float*)d_in[18];
  const float* w2            = (const float*)d_in[19];
  const float* b2            = (const float*)d_in[20];

  const size_t KV_BYTES = 2ull * 32 * 4096 * 256 * sizeof(u16);  // 128 MiB
  bool fast = ws_size >= KV_BYTES + (1u << 20);

  char* ws = (char*)d_ws;
  if (fast) {
    u16* kbuf    = (u16*)ws;                              // 64 MB
    u16* vbuf    = (u16*)(ws + KV_BYTES / 2);             // 64 MB
    char* base   = ws + KV_BYTES;
    float* slots = (float*)base;                          // 256 KB
    float* qbuf  = (float*)(base + 262144);               // 256 KB
    float* U     = (float*)(base + 524288);               // 256 KB
    float* S     = (float*)(base + 786432);               // 4 KB

    k_slots_init<<<256, 256, 0, stream>>>(slots_mu, slots_logsig, slots);
    k_proj<<<4096, 256, 0, stream>>>(inputs, ln_in_w, ln_in_b, Wk, Wv, kbuf, vbuf);

    for (int it = 0; it < 3; ++it) {
      hipMemsetAsync(U, 0, (65536 + 1024) * sizeof(float), stream);
      k_qproj<<<256, 256, 0, stream>>>(slots, ln_s_w, ln_s_b, Wq, qbuf);
      k_attn<<<dim3(32, 32), 256, 0, stream>>>(qbuf, kbuf, vbuf, U, S);
      k_slot_update<<<256, 256, 0, stream>>>(U, S, slots, Wc, w_ih, w_hh, b_ih, b_hh,
                                             ln_m_w, ln_m_b, w1, b1, w2, b2,
                                             (float*)d_out, it == 2 ? 1 : 0);
    }
  } else {
    float* slots = (float*)ws;                 // 256 KB
    float* qbuf  = (float*)(ws + 262144);      // 256 KB
    float* U     = (float*)(ws + 524288);      // 256 KB
    float* S     = (float*)(ws + 786432);      // 4 KB

    k_slots_init<<<256, 256, 0, stream>>>(slots_mu, slots_logsig, slots);
    for (int it = 0; it < 3; ++it) {
      hipMemsetAsync(U, 0, (65536 + 1024) * sizeof(float), stream);
      k_qproj<<<256, 256, 0, stream>>>(slots, ln_s_w, ln_s_b, Wq, qbuf);
      k_fused_attn<<<dim3(128, 32), 256, 0, stream>>>(inputs, ln_in_w, ln_in_b,
                                                      Wk, Wv, qbuf, U, S);
      k_slot_update<<<256, 256, 0, stream>>>(U, S, slots, Wc, w_ih, w_hh, b_ih, b_hh,
                                             ln_m_w, ln_m_b, w1, b1, w2, b2,
                                             (float*)d_out, it == 2 ? 1 : 0);
    }
  }
}